// Round 7
// baseline (223.326 us; speedup 1.0000x reference)
//
#include <hip/hip_runtime.h>
#include <hip/hip_bf16.h>
#include <math.h>

typedef short bf16x8 __attribute__((ext_vector_type(8)));   // 8 bf16 in 4 VGPRs
typedef float f32x16 __attribute__((ext_vector_type(16)));  // 32x32 MFMA acc

#define NB 8192
#define ND 256
#define NCLSR 100         // label values 0..99
#define BK 64             // K-chunk staged in LDS per iteration
#define INV_T 20.0f       // 1/TEMPERATURE
#define LOG2E_T 28.853900817779268f   // 20*log2(e): exp(20x) = 2^(x*this)
#define HI_THR 1.2026042e6f           // exp(14): any cos>0.7 element exceeds this
#define SELF_TERM 4.85165195e8f       // exp(20)

// ---------------- Kernel 1: row L2-normalize -> bf16 copy; zero accumulators --------
__global__ __launch_bounds__(256) void normalize_kernel(
    const float* __restrict__ feat, unsigned short* __restrict__ fb,
    float* __restrict__ hsum, float* __restrict__ nhighf,
    float* __restrict__ possum) {
    const int wave = threadIdx.x >> 6;
    const int lane = threadIdx.x & 63;
    const int row  = blockIdx.x * 4 + wave;
    float4 v = reinterpret_cast<const float4*>(feat + (size_t)row * ND)[lane];
    float ss = v.x * v.x + v.y * v.y + v.z * v.z + v.w * v.w;
    #pragma unroll
    for (int off = 32; off > 0; off >>= 1) ss += __shfl_xor(ss, off);
    const float inv = rsqrtf(ss);
    ushort4 o;
    __hip_bfloat16 h0 = __float2bfloat16(v.x * inv); o.x = *reinterpret_cast<unsigned short*>(&h0);
    __hip_bfloat16 h1 = __float2bfloat16(v.y * inv); o.y = *reinterpret_cast<unsigned short*>(&h1);
    __hip_bfloat16 h2 = __float2bfloat16(v.z * inv); o.z = *reinterpret_cast<unsigned short*>(&h2);
    __hip_bfloat16 h3 = __float2bfloat16(v.w * inv); o.w = *reinterpret_cast<unsigned short*>(&h3);
    reinterpret_cast<ushort4*>(fb + (size_t)NB * 0 + (size_t)row * ND)[lane] = o;
    if (blockIdx.x < 32) {
        const int i = (blockIdx.x << 8) + threadIdx.x;
        hsum[i] = 0.f;
        nhighf[i] = 0.f;
    } else if (blockIdx.x == 32 && threadIdx.x == 0) {
        possum[0] = 0.f;
    }
}

// ---------------- Kernel 2: triangular sim tiles, 32x32x16 MFMA ----------
// 2080 blocks = lower triangle (bi >= bj). Block: 4 waves, 128x128 tile; wave 64x64
// as 2x2 frags of v_mfma_f32_32x32x16_bf16 (a/b frags are 4 VGPRs each -> K-loop
// peak regs ~105, fits __launch_bounds__(256,4) without spilling the 64-reg acc;
// R6's 127 MB WRITE_SIZE was acc spill at the 16x16x32 layout's 148-reg peak).
// BK=64 LDS staging via global_load_lds width-16, XOR-granule swizzle in the
// GLOBAL address (LDS side lane-contiguous). Row/col exp-sum partials -> Q slots,
// positive-pair cos -> one atomicAdd per block.
__global__ __launch_bounds__(256, 4) void sim_kernel(
    const unsigned short* __restrict__ fb, const int* __restrict__ labels,
    float* __restrict__ Q, float* __restrict__ hsum,
    float* __restrict__ nhighf, float* __restrict__ possum) {
    __shared__ __align__(16) unsigned short ldsA[128 * BK];   // 16 KB
    __shared__ __align__(16) unsigned short ldsB[128 * BK];   // 16 KB
    __shared__ float ldsRow[2][128];
    __shared__ float ldsCol[2][128];
    __shared__ int   ldsLab[256];          // [0..127]=row labels, [128..255]=col labels
    __shared__ float ldsP[4];              // per-wave possum partials

    // triangular decode: t -> (bi, bj), bi >= bj
    const int t = blockIdx.x;
    int bi = (int)((sqrtf((float)(8 * t + 1)) - 1.0f) * 0.5f);
    while ((bi + 1) * (bi + 2) / 2 <= t) ++bi;
    while (bi * (bi + 1) / 2 > t) --bi;
    const int bj = t - bi * (bi + 1) / 2;
    const int I0 = bi << 7;
    const int J0 = bj << 7;
    const bool isdiag = (bi == bj);

    const int tid  = threadIdx.x;
    const int wave = tid >> 6;
    const int lane = tid & 63;
    const int wy = wave >> 1, wx = wave & 1;
    const int l31  = lane & 31;
    const int half = lane >> 5;
    const bool dw = isdiag && (wy == wx);

    if (tid < 128) ldsLab[tid] = labels[I0 + tid];
    else           ldsLab[tid] = labels[J0 + tid - 128];

    int offRC[4];
    #pragma unroll
    for (int c = 0; c < 4; ++c) {
        const int Lg = (c << 6) + lane;
        const int row_loc = (wave << 5) + (Lg >> 3);
        const int g = (Lg & 7) ^ ((Lg >> 3) & 7);
        offRC[c] = row_loc * ND + (g << 3);
    }
    const unsigned short* baseA = fb + (size_t)I0 * ND;
    const unsigned short* baseB = fb + (size_t)J0 * ND;

    f32x16 acc[2][2];
    #pragma unroll
    for (int fy = 0; fy < 2; ++fy)
        #pragma unroll
        for (int fx = 0; fx < 2; ++fx)
            #pragma unroll
            for (int e = 0; e < 16; ++e) acc[fy][fx][e] = 0.f;

    for (int kk = 0; kk < ND; kk += BK) {
        __syncthreads();
        #pragma unroll
        for (int c = 0; c < 4; ++c) {
            __builtin_amdgcn_global_load_lds(
                (const __attribute__((address_space(1))) void*)(baseA + offRC[c] + kk),
                (__attribute__((address_space(3))) void*)(ldsA + (wave << 11) + (c << 9)),
                16, 0, 0);
            __builtin_amdgcn_global_load_lds(
                (const __attribute__((address_space(1))) void*)(baseB + offRC[c] + kk),
                (__attribute__((address_space(3))) void*)(ldsB + (wave << 11) + (c << 9)),
                16, 0, 0);
        }
        __syncthreads();

        #pragma unroll
        for (int s = 0; s < 4; ++s) {      // four k-steps of 16 within BK=64
            bf16x8 a[2], b[2];
            // lane reads A[row][s*16 + half*8 .. +8]; granule idx = s*2+half,
            // phys = idx ^ (row&7); row&7 == lane&7 for both frags
            const int gp = ((s << 1) + half) ^ (lane & 7);
            #pragma unroll
            for (int f = 0; f < 2; ++f) {
                const int rowA = (wy << 6) + (f << 5) + l31;
                const int rowB = (wx << 6) + (f << 5) + l31;
                a[f] = *reinterpret_cast<const bf16x8*>(ldsA + rowA * BK + (gp << 3));
                b[f] = *reinterpret_cast<const bf16x8*>(ldsB + rowB * BK + (gp << 3));
            }
            #pragma unroll
            for (int fy = 0; fy < 2; ++fy)
                #pragma unroll
                for (int fx = 0; fx < 2; ++fx)
                    acc[fy][fx] = __builtin_amdgcn_mfma_f32_32x32x16_bf16(
                        a[fy], b[fx], acc[fy][fx], 0, 0, 0);
        }
    }

    // Epilogue. C/D layout (m74/m101-verified): col = l31,
    // row = (reg&3) + 8*(reg>>2) + 4*half.
    const int rb = I0 + (wy << 6);
    const int cb = J0 + (wx << 6);
    int lcolr[2];
    #pragma unroll
    for (int fx = 0; fx < 2; ++fx) lcolr[fx] = ldsLab[128 + (wx << 6) + (fx << 5) + l31];

    int anyhigh = 0;
    float cs[2] = {0.f, 0.f};
    float pp = 0.f;
    #pragma unroll
    for (int fy = 0; fy < 2; ++fy) {
        #pragma unroll
        for (int reg = 0; reg < 16; ++reg) {
            const int rloc = (reg & 3) + ((reg >> 2) << 3) + (half << 2);  // 0..31
            const int row_local = (wy << 6) + (fy << 5) + rloc;
            const int lrow = ldsLab[row_local];
            const bool isdiag_lane = dw && (l31 == rloc);
            float d = 0.f;
            #pragma unroll
            for (int fx = 0; fx < 2; ++fx) {
                const float a = acc[fy][fx][reg];
                float e = exp2f(a * LOG2E_T);
                const bool diag_el = (fx == fy) && isdiag_lane;
                if (diag_el) e = 0.f;
                d += e;
                cs[fx] += e;
                if (lcolr[fx] == lrow && !diag_el) pp += a;
            }
            anyhigh |= (d > HI_THR);
            #pragma unroll
            for (int off = 16; off > 0; off >>= 1) d += __shfl_xor(d, off);
            if (l31 == 0)
                ldsRow[wx][row_local] = d;
        }
    }
    if (!isdiag) {
        #pragma unroll
        for (int fx = 0; fx < 2; ++fx) {
            cs[fx] += __shfl_xor(cs[fx], 32);
        }
        if (half == 0) {
            #pragma unroll
            for (int fx = 0; fx < 2; ++fx)
                ldsCol[wy][(wx << 6) + (fx << 5) + l31] = cs[fx];
        }
    }
    #pragma unroll
    for (int off = 32; off > 0; off >>= 1) pp += __shfl_xor(pp, off);
    if (lane == 0) ldsP[wave] = pp;

    __syncthreads();
    if (tid < 128) {
        Q[(size_t)(bi * 64 + bj) * 128 + tid] = ldsRow[0][tid] + ldsRow[1][tid];
    } else if (!isdiag) {
        const int c2 = tid - 128;
        Q[(size_t)(bj * 64 + bi) * 128 + c2] = ldsCol[0][c2] + ldsCol[1][c2];
    }
    if (tid == 0) {
        const float scale = isdiag ? 1.f : 2.f;
        atomicAdd(possum, (ldsP[0] + ldsP[1] + ldsP[2] + ldsP[3]) * scale);
    }

    // Cold path: some element had sim > 14 (cos > 0.7) -> relax-term bookkeeping.
    if (__any(anyhigh)) {
        float hc[2] = {0.f, 0.f}, nc[2] = {0.f, 0.f};
        #pragma unroll
        for (int fy = 0; fy < 2; ++fy) {
            #pragma unroll
            for (int reg = 0; reg < 16; ++reg) {
                const int rloc = (reg & 3) + ((reg >> 2) << 3) + (half << 2);
                const int row  = rb + (fy << 5) + rloc;
                const int lrow = ldsLab[(wy << 6) + (fy << 5) + rloc];
                float hs = 0.f, nh = 0.f;
                #pragma unroll
                for (int fx = 0; fx < 2; ++fx) {
                    const int col = cb + (fx << 5) + l31;
                    const float a = acc[fy][fx][reg];
                    if (a > 0.7f && lcolr[fx] == lrow && col != row) {
                        const float e = exp2f(a * LOG2E_T);
                        hs += e; nh += 1.f;
                        hc[fx] += e; nc[fx] += 1.f;
                    }
                }
                #pragma unroll
                for (int off = 16; off > 0; off >>= 1) {
                    hs += __shfl_xor(hs, off);
                    nh += __shfl_xor(nh, off);
                }
                if (l31 == 0 && nh > 0.f) {
                    atomicAdd(&hsum[row], hs);
                    atomicAdd(&nhighf[row], nh);
                }
            }
        }
        if (!isdiag) {
            #pragma unroll
            for (int fx = 0; fx < 2; ++fx) {
                hc[fx] += __shfl_xor(hc[fx], 32);
                nc[fx] += __shfl_xor(nc[fx], 32);
            }
            if (half == 0) {
                #pragma unroll
                for (int fx = 0; fx < 2; ++fx) {
                    if (nc[fx] > 0.f) {
                        atomicAdd(&hsum[cb + (fx << 5) + l31], hc[fx]);
                        atomicAdd(&nhighf[cb + (fx << 5) + l31], nc[fx]);
                    }
                }
            }
        }
    }
}

// ---------------- Kernel 2b: fold Q partials into denom ----------------
__global__ __launch_bounds__(256) void reduce_kernel(
    const float* __restrict__ Q, float* __restrict__ denom) {
    const int g = blockIdx.x;
    const int t = threadIdx.x;
    const int r = t & 127;
    const int sh = t >> 7;
    const float* base = Q + (size_t)g * 64 * 128;
    float s = 0.f;
    #pragma unroll 8
    for (int i = 0; i < 32; ++i)
        s += base[(size_t)(sh * 32 + i) * 128 + r];
    __shared__ float red[256];
    red[t] = s;
    __syncthreads();
    if (t < 128) denom[g * 128 + t] = red[t] + red[t + 128];
}

// ---------------- Kernel 3: scalar finalize (w/ label histogram) ----------------
__global__ __launch_bounds__(256) void finalize_kernel(
    const float* __restrict__ denom, const float* __restrict__ hsum,
    const float* __restrict__ nhighf, const float* __restrict__ possum,
    const int* __restrict__ labels, float* __restrict__ out) {
    const int tid = threadIdx.x;
    __shared__ int cnt[128];
    if (tid < 128) cnt[tid] = 0;
    __syncthreads();
    for (int i = tid; i < NB; i += 256)
        atomicAdd(&cnt[labels[i]], 1);
    __syncthreads();
    float NT = 0.f;
    if (tid < NCLSR) {
        float nc = (float)cnt[tid];
        NT = nc * (nc - 1.f);
    }
    float SL = 0.f, RL = 0.f, NH = 0.f;
    for (int i = tid; i < NB; i += 256) {
        float np = (float)(cnt[labels[i]] - 1);
        SL += np * logf(denom[i] + 1e-8f);
        float h = hsum[i];
        if (h > 0.f) RL += logf(h + SELF_TERM);
        NH += nhighf[i];
    }
    #pragma unroll
    for (int off = 32; off > 0; off >>= 1) {
        NT += __shfl_xor(NT, off);
        SL += __shfl_xor(SL, off);
        RL += __shfl_xor(RL, off);
        NH += __shfl_xor(NH, off);
    }
    __shared__ float part[4][4];
    if ((tid & 63) == 0) {
        int w = tid >> 6;
        part[w][0] = NT; part[w][1] = SL; part[w][2] = RL; part[w][3] = NH;
    }
    __syncthreads();
    if (tid == 0) {
        float nt = part[0][0] + part[1][0] + part[2][0] + part[3][0];
        float sl = part[0][1] + part[1][1] + part[2][1] + part[3][1];
        float rl = part[0][2] + part[1][2] + part[2][2] + part[3][2];
        float nh = part[0][3] + part[1][3] + part[2][3] + part[3][3];
        float pos_sim = possum[0] * INV_T;
        float scl   = (nt > 0.f) ? (sl - pos_sim) / nt : 0.f;
        float relax = (nh > 0.f) ? rl / nh : 0.f;
        out[0] = scl + relax;
    }
}

extern "C" void kernel_launch(void* const* d_in, const int* in_sizes, int n_in,
                              void* d_out, int out_size, void* d_ws, size_t ws_size,
                              hipStream_t stream) {
    const float* feat  = (const float*)d_in[0];
    const int* labels  = (const int*)d_in[1];
    float* out = (float*)d_out;

    char* ws = (char*)d_ws;
    unsigned short* fb = (unsigned short*)ws;                                // 4 MB
    float* Q      = (float*)(ws + (size_t)NB * ND * sizeof(unsigned short)); // 2 MB
    float* denom  = Q + 64 * 64 * 128;
    float* hsum   = denom  + NB;
    float* nhighf = hsum   + NB;
    float* possum = nhighf + NB;          // 1 float

    normalize_kernel<<<NB / 4, 256, 0, stream>>>(feat, fb, hsum, nhighf, possum);
    sim_kernel<<<2080, 256, 0, stream>>>(fb, labels, Q, hsum, nhighf, possum);
    reduce_kernel<<<64, 256, 0, stream>>>(Q, denom);
    finalize_kernel<<<1, 256, 0, stream>>>(denom, hsum, nhighf, possum, labels, out);
}

// Round 8
// 178.776 us; speedup vs baseline: 1.2492x; 1.2492x over previous
//
#include <hip/hip_runtime.h>
#include <hip/hip_bf16.h>
#include <math.h>

typedef short bf16x8 __attribute__((ext_vector_type(8)));   // 8 bf16 in 4 VGPRs
typedef float f32x16 __attribute__((ext_vector_type(16)));  // 32x32 MFMA acc

#define NB 8192
#define ND 256
#define NCLSR 100         // label values 0..99
#define BK 64             // K-chunk staged in LDS per iteration
#define INV_T 20.0f       // 1/TEMPERATURE
#define LOG2E_T 28.853900817779268f   // 20*log2(e): exp(20x) = 2^(x*this)
#define SELF_TERM 4.85165195e8f       // exp(20)

// ---------------- Kernel 1: row L2-normalize -> bf16 copy; zero accumulators --------
__global__ __launch_bounds__(256) void normalize_kernel(
    const float* __restrict__ feat, unsigned short* __restrict__ fb,
    float* __restrict__ hsum, float* __restrict__ nhighf,
    float* __restrict__ possum) {
    const int wave = threadIdx.x >> 6;
    const int lane = threadIdx.x & 63;
    const int row  = blockIdx.x * 4 + wave;
    float4 v = reinterpret_cast<const float4*>(feat + (size_t)row * ND)[lane];
    float ss = v.x * v.x + v.y * v.y + v.z * v.z + v.w * v.w;
    #pragma unroll
    for (int off = 32; off > 0; off >>= 1) ss += __shfl_xor(ss, off);
    const float inv = rsqrtf(ss);
    ushort4 o;
    __hip_bfloat16 h0 = __float2bfloat16(v.x * inv); o.x = *reinterpret_cast<unsigned short*>(&h0);
    __hip_bfloat16 h1 = __float2bfloat16(v.y * inv); o.y = *reinterpret_cast<unsigned short*>(&h1);
    __hip_bfloat16 h2 = __float2bfloat16(v.z * inv); o.z = *reinterpret_cast<unsigned short*>(&h2);
    __hip_bfloat16 h3 = __float2bfloat16(v.w * inv); o.w = *reinterpret_cast<unsigned short*>(&h3);
    reinterpret_cast<ushort4*>(fb + (size_t)row * ND)[lane] = o;
    if (blockIdx.x < 32) {
        const int i = (blockIdx.x << 8) + threadIdx.x;
        hsum[i] = 0.f;
        nhighf[i] = 0.f;
    } else if (blockIdx.x == 32 && threadIdx.x == 0) {
        possum[0] = 0.f;
    }
}

// ---------------- Kernel 2: triangular sim tiles, 8 waves, 32x32x16 MFMA ----------
// 2080 blocks = lower triangle (bi >= bj). Block: 512 threads = 8 waves; 128x128
// tile; wave tile 64x32 as 2x1 frags of v_mfma_f32_32x32x16_bf16 -> 32 acc
// regs/lane. __launch_bounds__(512,4): 128 regs/wave, est. use ~80 -> no spill
// (R6/R7's 127-410 MB WRITE_SIZE was acc spill: 64 acc regs/lane can't fit any
// >=3-wave/EU budget once MFMA operands land in the unified file).
// BK=64 staging via global_load_lds width-16, XOR-granule swizzle in the GLOBAL
// address. Row/col exp-sum partials -> Q slots (plain stores), positive-pair cos
// -> one atomicAdd per block. wave w: wy=w>>2 rows [wy*64,+64), wx=w&3 cols
// [wx*32,+32); w also stages rows [w*16,+16) of A and B.
__global__ __launch_bounds__(512, 4) void sim_kernel(
    const unsigned short* __restrict__ fb, const int* __restrict__ labels,
    float* __restrict__ Q, float* __restrict__ hsum,
    float* __restrict__ nhighf, float* __restrict__ possum) {
    __shared__ __align__(16) unsigned short ldsA[128 * BK];   // 16 KB
    __shared__ __align__(16) unsigned short ldsB[128 * BK];   // 16 KB
    __shared__ float ldsRow[4][128];       // [wx][local row] partial row sums
    __shared__ float ldsCol[2][128];       // [wy][local col] partial col sums
    __shared__ int   ldsLab[256];          // [0..127]=row labels, [128..255]=col labels
    __shared__ float ldsP[8];              // per-wave possum partials

    // triangular decode: t -> (bi, bj), bi >= bj
    const int t = blockIdx.x;
    int bi = (int)((sqrtf((float)(8 * t + 1)) - 1.0f) * 0.5f);
    while ((bi + 1) * (bi + 2) / 2 <= t) ++bi;
    while (bi * (bi + 1) / 2 > t) --bi;
    const int bj = t - bi * (bi + 1) / 2;
    const int I0 = bi << 7;
    const int J0 = bj << 7;
    const bool isdiag = (bi == bj);

    const int tid  = threadIdx.x;
    const int wave = tid >> 6;
    const int lane = tid & 63;
    const int wy = wave >> 2;              // 0..1 : row half
    const int wx = wave & 3;               // 0..3 : col quarter
    const int l31  = lane & 31;
    const int half = lane >> 5;

    if (tid < 128) ldsLab[tid] = labels[I0 + tid];
    else if (tid < 256) ldsLab[tid] = labels[J0 + tid - 128];

    // staging offsets: wave stages rows [w*16, +16); chunk c: Lg=(c<<6)+lane,
    // row_loc = w*16 + (Lg>>3), swizzled granule g = (Lg&7)^((Lg>>3)&7)
    int offRC[2];
    #pragma unroll
    for (int c = 0; c < 2; ++c) {
        const int Lg = (c << 6) + lane;
        const int row_loc = (wave << 4) + (Lg >> 3);
        const int g = (Lg & 7) ^ ((Lg >> 3) & 7);
        offRC[c] = row_loc * ND + (g << 3);
    }
    const unsigned short* baseA = fb + (size_t)I0 * ND;
    const unsigned short* baseB = fb + (size_t)J0 * ND;

    f32x16 acc[2];
    #pragma unroll
    for (int fy = 0; fy < 2; ++fy)
        #pragma unroll
        for (int e = 0; e < 16; ++e) acc[fy][e] = 0.f;

    for (int kk = 0; kk < ND; kk += BK) {
        __syncthreads();                   // protect LDS from prior-iter readers
        #pragma unroll
        for (int c = 0; c < 2; ++c) {
            __builtin_amdgcn_global_load_lds(
                (const __attribute__((address_space(1))) void*)(baseA + offRC[c] + kk),
                (__attribute__((address_space(3))) void*)(ldsA + (wave << 10) + (c << 9)),
                16, 0, 0);
            __builtin_amdgcn_global_load_lds(
                (const __attribute__((address_space(1))) void*)(baseB + offRC[c] + kk),
                (__attribute__((address_space(3))) void*)(ldsB + (wave << 10) + (c << 9)),
                16, 0, 0);
        }
        __syncthreads();                   // staging visible

        #pragma unroll
        for (int s = 0; s < 4; ++s) {      // four k-steps of 16 within BK=64
            // granule q = s*2+half, phys slot = q ^ (row&7); row&7 == l31&7
            const int gp = ((s << 1) + half) ^ (l31 & 7);
            const int rowB = (wx << 5) + l31;
            bf16x8 b = *reinterpret_cast<const bf16x8*>(ldsB + rowB * BK + (gp << 3));
            bf16x8 a[2];
            #pragma unroll
            for (int fy = 0; fy < 2; ++fy) {
                const int rowA = (wy << 6) + (fy << 5) + l31;
                a[fy] = *reinterpret_cast<const bf16x8*>(ldsA + rowA * BK + (gp << 3));
            }
            #pragma unroll
            for (int fy = 0; fy < 2; ++fy)
                acc[fy] = __builtin_amdgcn_mfma_f32_32x32x16_bf16(a[fy], b, acc[fy], 0, 0, 0);
        }
    }

    // Epilogue. C/D layout (m74/m101-verified, R7-validated): col = l31,
    // row = (reg&3) + 8*(reg>>2) + 4*half.
    const int cb = J0 + (wx << 5);
    const int lcol = ldsLab[128 + (wx << 5) + l31];   // this lane's column label

    int anyhigh = 0;
    float cs = 0.f;                        // col partial (this lane's col)
    float pp = 0.f;                        // positive-pair cos partial
    #pragma unroll
    for (int fy = 0; fy < 2; ++fy) {
        const bool dband = isdiag && (((wy << 1) + fy) == wx);
        #pragma unroll
        for (int reg = 0; reg < 16; ++reg) {
            const int rloc = (reg & 3) + ((reg >> 2) << 3) + (half << 2);  // 0..31
            const int row_local = (wy << 6) + (fy << 5) + rloc;
            const int lrow = ldsLab[row_local];
            const float a = acc[fy][reg];
            const bool diag_el = dband && (l31 == rloc);
            float e = exp2f(a * LOG2E_T);
            if (diag_el) e = 0.f;
            cs += e;
            if (lcol == lrow && !diag_el) pp += a;
            anyhigh |= (!diag_el && a > 0.7f);
            float d = e;
            #pragma unroll
            for (int off = 16; off > 0; off >>= 1) d += __shfl_xor(d, off);
            if (l31 == 0)
                ldsRow[wx][row_local] = d;
        }
    }
    cs += __shfl_xor(cs, 32);              // combine halves (same column)
    if (half == 0 && !isdiag)
        ldsCol[wy][(wx << 5) + l31] = cs;
    #pragma unroll
    for (int off = 32; off > 0; off >>= 1) pp += __shfl_xor(pp, off);
    if (lane == 0) ldsP[wave] = pp;

    __syncthreads();
    if (tid < 128) {
        Q[(size_t)(bi * 64 + bj) * 128 + tid] =
            ldsRow[0][tid] + ldsRow[1][tid] + ldsRow[2][tid] + ldsRow[3][tid];
    } else if (tid < 256 && !isdiag) {
        const int c2 = tid - 128;
        Q[(size_t)(bj * 64 + bi) * 128 + c2] = ldsCol[0][c2] + ldsCol[1][c2];
    }
    if (tid == 0) {
        const float scale = isdiag ? 1.f : 2.f;
        atomicAdd(possum, (ldsP[0] + ldsP[1] + ldsP[2] + ldsP[3] +
                           ldsP[4] + ldsP[5] + ldsP[6] + ldsP[7]) * scale);
    }

    // Cold path: some off-diag element had cos > 0.7 -> relax-term bookkeeping.
    if (__any(anyhigh)) {
        float hc = 0.f, nc = 0.f;
        #pragma unroll
        for (int fy = 0; fy < 2; ++fy) {
            const bool dband = isdiag && (((wy << 1) + fy) == wx);
            #pragma unroll
            for (int reg = 0; reg < 16; ++reg) {
                const int rloc = (reg & 3) + ((reg >> 2) << 3) + (half << 2);
                const int row_local = (wy << 6) + (fy << 5) + rloc;
                const int lrow = ldsLab[row_local];
                const float a = acc[fy][reg];
                const bool diag_el = dband && (l31 == rloc);
                float hs = 0.f, nh = 0.f;
                if (a > 0.7f && lcol == lrow && !diag_el) {
                    const float e = exp2f(a * LOG2E_T);
                    hs = e; nh = 1.f;
                    hc += e; nc += 1.f;
                }
                #pragma unroll
                for (int off = 16; off > 0; off >>= 1) {
                    hs += __shfl_xor(hs, off);
                    nh += __shfl_xor(nh, off);
                }
                if (l31 == 0 && nh > 0.f) {
                    atomicAdd(&hsum[I0 + row_local], hs);
                    atomicAdd(&nhighf[I0 + row_local], nh);
                }
            }
        }
        if (!isdiag) {
            hc += __shfl_xor(hc, 32);
            nc += __shfl_xor(nc, 32);
            if (half == 0 && nc > 0.f) {
                atomicAdd(&hsum[cb + l31], hc);
                atomicAdd(&nhighf[cb + l31], nc);
            }
        }
    }
}

// ---------------- Kernel 2b: fold Q partials into denom ----------------
__global__ __launch_bounds__(256) void reduce_kernel(
    const float* __restrict__ Q, float* __restrict__ denom) {
    const int g = blockIdx.x;
    const int t = threadIdx.x;
    const int r = t & 127;
    const int sh = t >> 7;
    const float* base = Q + (size_t)g * 64 * 128;
    float s = 0.f;
    #pragma unroll 8
    for (int i = 0; i < 32; ++i)
        s += base[(size_t)(sh * 32 + i) * 128 + r];
    __shared__ float red[256];
    red[t] = s;
    __syncthreads();
    if (t < 128) denom[g * 128 + t] = red[t] + red[t + 128];
}

// ---------------- Kernel 3: scalar finalize (w/ label histogram) ----------------
__global__ __launch_bounds__(256) void finalize_kernel(
    const float* __restrict__ denom, const float* __restrict__ hsum,
    const float* __restrict__ nhighf, const float* __restrict__ possum,
    const int* __restrict__ labels, float* __restrict__ out) {
    const int tid = threadIdx.x;
    __shared__ int cnt[128];
    if (tid < 128) cnt[tid] = 0;
    __syncthreads();
    for (int i = tid; i < NB; i += 256)
        atomicAdd(&cnt[labels[i]], 1);
    __syncthreads();
    float NT = 0.f;
    if (tid < NCLSR) {
        float nc = (float)cnt[tid];
        NT = nc * (nc - 1.f);
    }
    float SL = 0.f, RL = 0.f, NH = 0.f;
    for (int i = tid; i < NB; i += 256) {
        float np = (float)(cnt[labels[i]] - 1);
        SL += np * logf(denom[i] + 1e-8f);
        float h = hsum[i];
        if (h > 0.f) RL += logf(h + SELF_TERM);
        NH += nhighf[i];
    }
    #pragma unroll
    for (int off = 32; off > 0; off >>= 1) {
        NT += __shfl_xor(NT, off);
        SL += __shfl_xor(SL, off);
        RL += __shfl_xor(RL, off);
        NH += __shfl_xor(NH, off);
    }
    __shared__ float part[4][4];
    if ((tid & 63) == 0) {
        int w = tid >> 6;
        part[w][0] = NT; part[w][1] = SL; part[w][2] = RL; part[w][3] = NH;
    }
    __syncthreads();
    if (tid == 0) {
        float nt = part[0][0] + part[1][0] + part[2][0] + part[3][0];
        float sl = part[0][1] + part[1][1] + part[2][1] + part[3][1];
        float rl = part[0][2] + part[1][2] + part[2][2] + part[3][2];
        float nh = part[0][3] + part[1][3] + part[2][3] + part[3][3];
        float pos_sim = possum[0] * INV_T;
        float scl   = (nt > 0.f) ? (sl - pos_sim) / nt : 0.f;
        float relax = (nh > 0.f) ? rl / nh : 0.f;
        out[0] = scl + relax;
    }
}

extern "C" void kernel_launch(void* const* d_in, const int* in_sizes, int n_in,
                              void* d_out, int out_size, void* d_ws, size_t ws_size,
                              hipStream_t stream) {
    const float* feat  = (const float*)d_in[0];
    const int* labels  = (const int*)d_in[1];
    float* out = (float*)d_out;

    char* ws = (char*)d_ws;
    unsigned short* fb = (unsigned short*)ws;                                // 4 MB
    float* Q      = (float*)(ws + (size_t)NB * ND * sizeof(unsigned short)); // 2 MB
    float* denom  = Q + 64 * 64 * 128;
    float* hsum   = denom  + NB;
    float* nhighf = hsum   + NB;
    float* possum = nhighf + NB;          // 1 float

    normalize_kernel<<<NB / 4, 256, 0, stream>>>(feat, fb, hsum, nhighf, possum);
    sim_kernel<<<2080, 512, 0, stream>>>(fb, labels, Q, hsum, nhighf, possum);
    reduce_kernel<<<64, 256, 0, stream>>>(Q, denom);
    finalize_kernel<<<1, 256, 0, stream>>>(denom, hsum, nhighf, possum, labels, out);
}